// Round 5
// baseline (232.616 us; speedup 1.0000x reference)
//
#include <hip/hip_runtime.h>

#define LLEN 8192
#define CG 16
#define NG 512   // b(16) * GROUPS(32)

typedef float f32x4 __attribute__((ext_vector_type(4)));

// One block per group. 1024 threads = 16 waves.
// Phase 1: wave w sums row w (coalesced float4).  Prep (softmax -> collapsed
// 3-tap vectors) runs on wave 0 into LDS.  Phase 2: each wave applies the
// sigmoid gate over two 256-column chunks, traversed in REVERSE chunk order
// (freshest L3 lines first), with non-temporal re-reads and NT stores.
__global__ __launch_bounds__(1024) void fused_kernel(const float* __restrict__ x,
                                                     const float* __restrict__ w1,
                                                     const float* __restrict__ b1,
                                                     const float* __restrict__ w3,
                                                     const float* __restrict__ b3,
                                                     float* __restrict__ out) {
    int g    = blockIdx.x;              // 0..511
    int wave = threadIdx.x >> 6;        // 0..15
    int lane = threadIdx.x & 63;
    __shared__ float S_lds[CG], F_lds[CG], L_lds[CG];
    __shared__ float V_lds[49];         // v0[0:16) v1[16:32) v2[32:48) cb[48]

    // ---------------- phase 1: row sums ----------------
    const float4* xr = reinterpret_cast<const float4*>(x + (size_t)(g * CG + wave) * LLEN);
    float s = 0.f;
    #pragma unroll
    for (int k = 0; k < 32; ++k) {
        float4 v = xr[k * 64 + lane];
        s += (v.x + v.y) + (v.z + v.w);
    }
    #pragma unroll
    for (int off = 32; off; off >>= 1)
        s += __shfl_down(s, off, 64);
    if (lane == 0) S_lds[wave] = s;
    if (threadIdx.x < CG) {
        size_t rb = (size_t)(g * CG + threadIdx.x) * LLEN;
        F_lds[threadIdx.x] = x[rb];
        L_lds[threadIdx.x] = x[rb + (LLEN - 1)];
    }
    __syncthreads();

    // ---------------- prep: softmax weights -> v0,v1,v2,cb ----------------
    if (wave == 0) {
        int i = lane & 15;
        const float invL = 1.0f / (float)LLEN;
        float s1 = 0.f, s2 = 0.f;
        #pragma unroll
        for (int k = 0; k < CG; ++k) {
            float Sk = S_lds[k], Fk = F_lds[k], Lk = L_lds[k];
            s1 += w1[i * CG + k] * Sk;
            const float* w = &w3[(i * CG + k) * 3];
            s2 += w[0] * (Sk - Lk) + w[1] * Sk + w[2] * (Sk - Fk);
        }
        float m1 = s1 * invL + b1[i];
        float m2 = s2 * invL + b3[i];

        float mx1 = m1, mx2 = m2;
        #pragma unroll
        for (int off = 8; off; off >>= 1) {
            mx1 = fmaxf(mx1, __shfl_xor(mx1, off, 16));
            mx2 = fmaxf(mx2, __shfl_xor(mx2, off, 16));
        }
        float e1 = __expf(m1 - mx1), e2 = __expf(m2 - mx2);
        float d1 = e1, d2 = e2;
        #pragma unroll
        for (int off = 8; off; off >>= 1) {
            d1 += __shfl_xor(d1, off, 16);
            d2 += __shfl_xor(d2, off, 16);
        }
        float a1 = e1 / d1, a2 = e2 / d2;

        float cb = a1 * b3[i] + a2 * b1[i];
        #pragma unroll
        for (int off = 8; off; off >>= 1) cb += __shfl_xor(cb, off, 16);

        float v0 = 0.f, v1v = 0.f, v2 = 0.f;
        #pragma unroll
        for (int k = 0; k < CG; ++k) {
            float a1k = __shfl(a1, k, 16);
            float a2k = __shfl(a2, k, 16);
            const float* w = &w3[(k * CG + i) * 3];
            v0  += a1k * w[0];
            v1v += a1k * w[1] + a2k * w1[k * CG + i];
            v2  += a1k * w[2];
        }
        if (lane < 16) {
            V_lds[i]      = v0;
            V_lds[16 + i] = v1v;
            V_lds[32 + i] = v2;
            if (lane == 0) V_lds[48] = cb;
        }
    }
    __syncthreads();

    // ---------------- phase 2: apply (reverse chunk order, NT re-reads) ----------
    const float cbv = V_lds[48];
    #pragma unroll 1
    for (int rep = 0; rep < 2; ++rep) {
        int c0 = (31 - wave - 16 * rep) * 256;      // chunks 31..16 then 15..0
        float w0 = cbv, w1a = cbv, w2a = cbv, w3a = cbv;
        f32x4 xv[CG];
        #pragma unroll
        for (int i = 0; i < CG; ++i) {
            size_t rb = ((size_t)(g * CG + i)) * LLEN + c0;
            f32x4 v = __builtin_nontemporal_load(
                reinterpret_cast<const f32x4*>(x + rb + 4 * lane));
            xv[i] = v;
            float le = 0.f, re = 0.f;
            if (c0 > 0)            le = x[rb - 1];
            if (c0 + 256 < LLEN)   re = x[rb + 256];
            float fl = __shfl_up(v.w, 1, 64);
            if (lane == 0)  fl = le;
            float fr = __shfl_down(v.x, 1, 64);
            if (lane == 63) fr = re;
            const float a0 = V_lds[i], a1 = V_lds[16 + i], a2 = V_lds[32 + i];
            w0  += a0 * fl  + a1 * v.x + a2 * v.y;
            w1a += a0 * v.x + a1 * v.y + a2 * v.z;
            w2a += a0 * v.y + a1 * v.z + a2 * v.w;
            w3a += a0 * v.z + a1 * v.w + a2 * fr;
        }
        const float s0 = 1.f / (1.f + __expf(-w0));
        const float s1 = 1.f / (1.f + __expf(-w1a));
        const float s2 = 1.f / (1.f + __expf(-w2a));
        const float s3 = 1.f / (1.f + __expf(-w3a));
        #pragma unroll
        for (int i = 0; i < CG; ++i) {
            size_t rb = ((size_t)(g * CG + i)) * LLEN + c0 + 4 * lane;
            f32x4 v = xv[i];
            f32x4 o4 = { v.x * s0, v.y * s1, v.z * s2, v.w * s3 };
            __builtin_nontemporal_store(o4, reinterpret_cast<f32x4*>(out + rb));
        }
    }
}

extern "C" void kernel_launch(void* const* d_in, const int* in_sizes, int n_in,
                              void* d_out, int out_size, void* d_ws, size_t ws_size,
                              hipStream_t stream) {
    const float* x  = (const float*)d_in[0];
    const float* w1 = (const float*)d_in[1];
    const float* b1 = (const float*)d_in[2];
    const float* w3 = (const float*)d_in[3];
    const float* b3 = (const float*)d_in[4];
    float* out = (float*)d_out;

    fused_kernel<<<NG, 1024, 0, stream>>>(x, w1, b1, w3, b3, out);
}